// Round 9
// baseline (135.326 us; speedup 1.0000x reference)
//
#include <hip/hip_runtime.h>
#include <hip/hip_bf16.h>
#include <math.h>

#define NN 50000
#define NE 1000000
#define FIN 128
#define FOUT 64
#define NEG 0.2f

#define NB   512      // dst-range superbuckets (500 used)
#define DPB  100      // dsts per superbucket; 500*100 = 50000 exact
#define NBUSED 500
#define TS   4096     // edges per sort tile
#define NT   245      // 244 full tiles + 576-edge tail (<= 256)
#define NTP  256      // padded row stride of transposed gofs
#define RCAP 2560     // raw/srt/evs capacity (mean 2000, sigma ~45 -> 12 sigma)
#define TILE_BLKS 245
#define GEMM_BLKS 391 // ceil(3125 strips / 8 waves)

using short8  = __attribute__((ext_vector_type(8))) short;
using floatx4 = __attribute__((ext_vector_type(4))) float;

static __device__ __forceinline__ short f2bf(float f) {
    __hip_bfloat16 h = __float2bfloat16(f);
    return *(short*)&h;
}

// Fused front kernel, 512 threads. Blocks [0,TILE_BLKS) = per-tile LDS
// counting-sort into 512 superbuckets; blocks [TILE_BLKS,+GEMM_BLKS) = MFMA
// gemm. Roles touch disjoint data and run concurrently.
__global__ __launch_bounds__(512) void k_front(
    const float* __restrict__ x, const float* __restrict__ W,
    const float* __restrict__ a_src, const float* __restrict__ a_dst,
    const int* __restrict__ ei,
    __hip_bfloat16* __restrict__ Whb, float* __restrict__ s_src,
    float* __restrict__ s_dst,
    unsigned* __restrict__ bdata, int* __restrict__ gofs)
{
    __shared__ int cnt[NB];            // 2 KB
    __shared__ int cur[NB];            // 2 KB
    __shared__ unsigned srt[TS];       // 16 KB
    __shared__ int wsum[8];

    const int tid  = threadIdx.x;
    const int lane = tid & 63;
    const int wv   = tid >> 6;

    if (blockIdx.x >= TILE_BLKS) {
        // ---------------- GEMM role ----------------
        // D = A(16x128)·B(128x64) via 4 K-steps x 4 N-tiles of
        // mfma_f32_16x16x32_bf16. A[m=lane&15][k=quad*8+j],
        // B[k=quad*8+j][n=lane&15], C: col=lane&15, row=quad*4+reg.
        const int col  = lane & 15;
        const int quad = lane >> 4;
        const int strip = (blockIdx.x - TILE_BLKS) * 8 + wv;
        if (strip >= NN / 16) return;          // 3125 strips
        const int row0 = strip * 16;

        short8 bfr[4][4];
        #pragma unroll
        for (int kk = 0; kk < 4; ++kk) {
            #pragma unroll
            for (int nt = 0; nt < 4; ++nt) {
                const float* wp = W + (kk * 32 + quad * 8) * FOUT + nt * 16 + col;
                #pragma unroll
                for (int j = 0; j < 8; ++j)
                    bfr[kk][nt][j] = f2bf(wp[j * FOUT]);
            }
        }

        floatx4 acc[4] = {{0.f,0.f,0.f,0.f},{0.f,0.f,0.f,0.f},
                          {0.f,0.f,0.f,0.f},{0.f,0.f,0.f,0.f}};

        const float* xrow = x + (size_t)(row0 + col) * FIN + quad * 8;
        #pragma unroll
        for (int kk = 0; kk < 4; ++kk) {
            const float4 u0 = *(const float4*)(xrow + kk * 32);
            const float4 u1 = *(const float4*)(xrow + kk * 32 + 4);
            short8 af;
            af[0] = f2bf(u0.x); af[1] = f2bf(u0.y);
            af[2] = f2bf(u0.z); af[3] = f2bf(u0.w);
            af[4] = f2bf(u1.x); af[5] = f2bf(u1.y);
            af[6] = f2bf(u1.z); af[7] = f2bf(u1.w);
            #pragma unroll
            for (int nt = 0; nt < 4; ++nt)
                acc[nt] = __builtin_amdgcn_mfma_f32_16x16x32_bf16(
                    af, bfr[kk][nt], acc[nt], 0, 0, 0);
        }

        const float av0 = a_src[col], av1 = a_src[16 + col];
        const float av2 = a_src[32 + col], av3 = a_src[48 + col];
        const float bv0 = a_dst[col], bv1 = a_dst[16 + col];
        const float bv2 = a_dst[32 + col], bv3 = a_dst[48 + col];

        float ps[4], pd[4];
        #pragma unroll
        for (int reg = 0; reg < 4; ++reg) {
            ps[reg] = acc[0][reg] * av0 + acc[1][reg] * av1
                    + acc[2][reg] * av2 + acc[3][reg] * av3;
            pd[reg] = acc[0][reg] * bv0 + acc[1][reg] * bv1
                    + acc[2][reg] * bv2 + acc[3][reg] * bv3;
        }

        #pragma unroll
        for (int nt = 0; nt < 4; ++nt)
            #pragma unroll
            for (int reg = 0; reg < 4; ++reg)
                Whb[(size_t)(row0 + quad * 4 + reg) * FOUT + nt * 16 + col] =
                    __float2bfloat16(acc[nt][reg]);

        #pragma unroll
        for (int off = 1; off < 16; off <<= 1) {
            #pragma unroll
            for (int reg = 0; reg < 4; ++reg) {
                ps[reg] += __shfl_xor(ps[reg], off);
                pd[reg] += __shfl_xor(pd[reg], off);
            }
        }
        if (col == 0) {
            #pragma unroll
            for (int reg = 0; reg < 4; ++reg) {
                s_src[row0 + quad * 4 + reg] = ps[reg];
                s_dst[row0 + quad * 4 + reg] = pd[reg];
            }
        }
        return;
    }

    // ---------------- TILESORT role ----------------
    const int tile = blockIdx.x;
    const int base = tile * TS;
    const int tcnt = (NE - base < TS) ? (NE - base) : TS;

    if (tid < NB) cnt[tid] = 0;
    __syncthreads();

    unsigned pk[8];
    #pragma unroll
    for (int j = 0; j < 8; ++j) {
        const int i = j * 512 + tid;
        if (i < tcnt) {
            const int e = base + i;
            const unsigned s = (unsigned)__builtin_nontemporal_load(ei + e);
            const unsigned d = (unsigned)__builtin_nontemporal_load(ei + NE + e);
            pk[j] = (s << 16) | d;
            atomicAdd(&cnt[d / DPB], 1);
        } else pk[j] = 0xFFFFFFFFu;
    }
    __syncthreads();

    // exclusive scan of cnt[0..512): 1 counter/thread, wave scans + combine
    {
        const int v = cnt[tid];
        int inc = v;
        #pragma unroll
        for (int off = 1; off < 64; off <<= 1) {
            const int t = __shfl_up(inc, off);
            if (lane >= off) inc += t;
        }
        if (lane == 63) wsum[wv] = inc;
        __syncthreads();
        int wb = 0;
        #pragma unroll
        for (int w = 0; w < 7; ++w) if (w < wv) wb += wsum[w];
        const int excl = wb + inc - v;
        cur[tid] = excl;
        gofs[(size_t)tile * NB + tid] = excl;
    }
    __syncthreads();

    #pragma unroll
    for (int j = 0; j < 8; ++j) {
        if (pk[j] != 0xFFFFFFFFu) {
            const int b = (int)(pk[j] & 0xffffu) / DPB;
            const int pos = atomicAdd(&cur[b], 1);
            srt[pos] = pk[j];
        }
    }
    __syncthreads();

    for (int i = tid; i < tcnt; i += 512)
        bdata[base + i] = srt[i];
}

// Transpose gofs[t][b] (245x512, stride NB) -> gofs_t[b][t] (512 rows,
// stride NTP=256). 128 blocks of 256 threads.
__global__ __launch_bounds__(256) void k_transp(
    const int* __restrict__ gofs, int* __restrict__ gofs_t)
{
    __shared__ int tb[32][33];
    const int bi = blockIdx.x & 15;    // 512/32 bucket tiles
    const int ti = blockIdx.x >> 4;    // 8 t-tiles cover 256 >= NT
    const int r = threadIdx.x >> 5;    // 0..7
    const int c = threadIdx.x & 31;
    for (int rr = r; rr < 32; rr += 8) {
        const int t = ti * 32 + rr;
        tb[rr][c] = (t < NT) ? gofs[(size_t)t * NB + bi * 32 + c] : 0;
    }
    __syncthreads();
    for (int rr = r; rr < 32; rr += 8) {
        const int b = bi * 32 + rr;
        gofs_t[(size_t)b * NTP + ti * 32 + c] = tb[c][rr];
    }
}

// Per-superbucket gather (100 dsts, ~2000 edges), 512 threads. Tile-segments
// now avg 8.2 words (was 2) -> ~4x less bdata line over-fetch. XCD swizzle:
// consecutive superbuckets (sharing bdata lines) -> same XCD. LDS counting-
// sort by dst with fused ev compute; wave=dst/lane=feature gather, unroll 8.
__global__ __launch_bounds__(512) void k_sortgather(
    const int* __restrict__ gofs_t, const unsigned* __restrict__ bdata,
    const float* __restrict__ s_src, const float* __restrict__ s_dst,
    const __hip_bfloat16* __restrict__ Whb, float* __restrict__ out)
{
    __shared__ unsigned raw[RCAP];     // 10 KB
    __shared__ unsigned srt[RCAP];     // 10 KB
    __shared__ float evs[RCAP];        // 10 KB
    __shared__ float sdl[DPB];
    __shared__ int cnt[128];
    __shared__ int ofs2[129];
    __shared__ int cur[128];
    __shared__ int wsum[8];

    const int b = (blockIdx.x & 7) * 64 + (blockIdx.x >> 3);  // bijective on 512
    if (b >= NBUSED) return;
    const int tid = threadIdx.x;
    const int lane = tid & 63;
    const int wv = tid >> 6;
    const int d0 = b * DPB;

    if (tid < 128) cnt[tid] = 0;
    if (tid < DPB) sdl[tid] = s_dst[d0 + tid];

    // this thread's tile-segment from coalesced transposed-gofs rows
    int c = 0, o = 0;
    if (tid < NT) {
        o = gofs_t[(size_t)b * NTP + tid];
        c = gofs_t[(size_t)(b + 1) * NTP + tid] - o;
    }
    int inc = c;
    #pragma unroll
    for (int off = 1; off < 64; off <<= 1) {
        const int t = __shfl_up(inc, off);
        if (lane >= off) inc += t;
    }
    if (lane == 63) wsum[wv] = inc;
    __syncthreads();
    int wb = 0;
    #pragma unroll
    for (int w = 0; w < 7; ++w) if (w < wv) wb += wsum[w];
    const int segbase = wb + inc - c;
    int tot = 0;
    #pragma unroll
    for (int w = 0; w < 8; ++w) tot += wsum[w];
    if (tot > RCAP) tot = RCAP;        // defensive (12-sigma headroom)

    for (int k = 0; k < c; ++k) {
        const int p = segbase + k;
        if (p < RCAP) raw[p] = bdata[(size_t)tid * TS + o + k];
    }
    __syncthreads();

    for (int i = tid; i < tot; i += 512)
        atomicAdd(&cnt[(int)(raw[i] & 0xffffu) - d0], 1);
    __syncthreads();

    // exclusive scan over 128 bins (wave 0, 2 bins/lane)
    if (tid < 64) {
        const int c0 = cnt[2 * tid];
        const int c1 = cnt[2 * tid + 1];
        const int s = c0 + c1;
        int in2 = s;
        #pragma unroll
        for (int off = 1; off < 64; off <<= 1) {
            const int t = __shfl_up(in2, off);
            if (tid >= off) in2 += t;
        }
        const int excl = in2 - s;
        ofs2[2 * tid]     = excl;
        ofs2[2 * tid + 1] = excl + c0;
        cur[2 * tid]      = excl;
        cur[2 * tid + 1]  = excl + c0;
        if (tid == 63) ofs2[128] = in2;
    }
    __syncthreads();

    // LDS scatter into dst order + fused ev compute
    for (int i = tid; i < tot; i += 512) {
        const unsigned p = raw[i];
        const int j = (int)(p & 0xffffu) - d0;
        const int pos = atomicAdd(&cur[j], 1);
        srt[pos] = p;
        float v = s_src[p >> 16] + sdl[j];
        v = (v > 0.f) ? v : NEG * v;
        evs[pos] = __expf(v);
    }
    __syncthreads();

    // gather: wave = dst, lane = feature; unroll 8 (8 Whb rows in flight)
    for (int j = wv; j < DPB; j += 8) {
        const int d = d0 + j;
        const int beg = ofs2[j];
        const int end = ofs2[j + 1];
        float acc = 0.f, den = 0.f;
        int i = beg;
        for (; i + 8 <= end; i += 8) {
            int ss[8]; float ee[8], w[8];
            #pragma unroll
            for (int k = 0; k < 8; ++k) {
                ss[k] = (int)(srt[i + k] >> 16);
                ee[k] = evs[i + k];
            }
            #pragma unroll
            for (int k = 0; k < 8; ++k)
                w[k] = __bfloat162float(Whb[(size_t)ss[k] * FOUT + lane]);
            #pragma unroll
            for (int k = 0; k < 8; ++k) {
                acc = fmaf(ee[k], w[k], acc);
                den += ee[k];
            }
        }
        for (; i < end; ++i) {
            const int s0 = (int)(srt[i] >> 16);
            const float e0 = evs[i];
            acc = fmaf(e0, __bfloat162float(Whb[(size_t)s0 * FOUT + lane]), acc);
            den += e0;
        }
        const float r = acc / (den + 1e-16f);
        out[(size_t)d * FOUT + lane] = (r > 0.f) ? r : expm1f(r);
    }
}

extern "C" void kernel_launch(void* const* d_in, const int* in_sizes, int n_in,
                              void* d_out, int out_size, void* d_ws, size_t ws_size,
                              hipStream_t stream)
{
    const float* x     = (const float*)d_in[0];
    const int*   ei    = (const int*)d_in[1];   // [2,E]: src = ei[0..E), dst = ei[E..2E)
    const float* W     = (const float*)d_in[2];
    const float* a_src = (const float*)d_in[3];
    const float* a_dst = (const float*)d_in[4];
    float* out = (float*)d_out;

    // Workspace: Whb 6.4 MB | s_src 200 KB | s_dst 200 KB | gofs 0.5 MB |
    // gofs_t 0.5 MB | bdata 4 MB  -> ~11.8 MB. No memsets needed.
    float* ws    = (float*)d_ws;
    __hip_bfloat16* Whb = (__hip_bfloat16*)ws;
    float* s_src = ws + (size_t)NN * FOUT / 2;
    float* s_dst = s_src + NN;
    int*   gofs  = (int*)(s_dst + NN);
    int*   gofs_t = gofs + (size_t)256 * NB;
    unsigned* bdata = (unsigned*)(gofs_t + (size_t)NB * NTP);

    k_front<<<TILE_BLKS + GEMM_BLKS, 512, 0, stream>>>(
        x, W, a_src, a_dst, ei, Whb, s_src, s_dst, bdata, gofs);
    k_transp<<<128, 256, 0, stream>>>(gofs, gofs_t);
    k_sortgather<<<512, 512, 0, stream>>>(gofs_t, bdata, s_src, s_dst,
                                          Whb, out);
}

// Round 10
// 129.854 us; speedup vs baseline: 1.0421x; 1.0421x over previous
//
#include <hip/hip_runtime.h>
#include <hip/hip_bf16.h>
#include <math.h>

#define NN 50000
#define NE 1000000
#define FIN 128
#define FOUT 64
#define NEG 0.2f

#define NB     1024   // dst-range buckets (1000 used)
#define DPB    50     // dsts per bucket; 1000*50 = 50000 exact
#define NBUSED 1000
#define TS     4096   // edges per sort tile
#define PADCAP 1280   // slab capacity per bucket (mean 1000, sigma 31.6 -> +8.9s)
#define TILE_BLKS 245 // 244 full tiles + 576-edge tail
#define GEMM_BLKS 391 // ceil(3125 strips / 8 waves)

using short8  = __attribute__((ext_vector_type(8))) short;
using floatx4 = __attribute__((ext_vector_type(4))) float;

static __device__ __forceinline__ short f2bf(float f) {
    __hip_bfloat16 h = __float2bfloat16(f);
    return *(short*)&h;
}

// Fused front kernel, 512 threads. Blocks [0,TILE_BLKS): per-tile LDS
// counting-sort by bucket, then DIRECT write of each bucket-segment into a
// contiguous per-bucket global slab (position from one atomicAdd per
// non-empty (tile,bucket) — ~250k atomics total). This replaces the
// gofs/transpose/segment-gather machinery that made sortgather staging
// latency-bound (r9 post-mortem). Blocks [TILE_BLKS,+GEMM_BLKS): MFMA gemm.
__global__ __launch_bounds__(512) void k_front(
    const float* __restrict__ x, const float* __restrict__ W,
    const float* __restrict__ a_src, const float* __restrict__ a_dst,
    const int* __restrict__ ei,
    __hip_bfloat16* __restrict__ Whb, float* __restrict__ s_src,
    float* __restrict__ s_dst,
    int* __restrict__ bcur, unsigned* __restrict__ bdata2)
{
    __shared__ int cnt[NB];            // 4 KB
    __shared__ int ofs[NB];            // 4 KB
    __shared__ int cur[NB];            // 4 KB
    __shared__ int gpos[NB];           // 4 KB
    __shared__ unsigned srt[TS];       // 16 KB
    __shared__ int wsum[8];

    const int tid  = threadIdx.x;
    const int lane = tid & 63;
    const int wv   = tid >> 6;

    if (blockIdx.x >= TILE_BLKS) {
        // ---------------- GEMM role ----------------
        // D = A(16x128)·B(128x64) via 4 K-steps x 4 N-tiles of
        // mfma_f32_16x16x32_bf16. A[m=lane&15][k=quad*8+j],
        // B[k=quad*8+j][n=lane&15], C: col=lane&15, row=quad*4+reg.
        const int col  = lane & 15;
        const int quad = lane >> 4;
        const int strip = (blockIdx.x - TILE_BLKS) * 8 + wv;
        if (strip >= NN / 16) return;          // 3125 strips
        const int row0 = strip * 16;

        short8 bfr[4][4];
        #pragma unroll
        for (int kk = 0; kk < 4; ++kk) {
            #pragma unroll
            for (int nt = 0; nt < 4; ++nt) {
                const float* wp = W + (kk * 32 + quad * 8) * FOUT + nt * 16 + col;
                #pragma unroll
                for (int j = 0; j < 8; ++j)
                    bfr[kk][nt][j] = f2bf(wp[j * FOUT]);
            }
        }

        floatx4 acc[4] = {{0.f,0.f,0.f,0.f},{0.f,0.f,0.f,0.f},
                          {0.f,0.f,0.f,0.f},{0.f,0.f,0.f,0.f}};

        const float* xrow = x + (size_t)(row0 + col) * FIN + quad * 8;
        #pragma unroll
        for (int kk = 0; kk < 4; ++kk) {
            const float4 u0 = *(const float4*)(xrow + kk * 32);
            const float4 u1 = *(const float4*)(xrow + kk * 32 + 4);
            short8 af;
            af[0] = f2bf(u0.x); af[1] = f2bf(u0.y);
            af[2] = f2bf(u0.z); af[3] = f2bf(u0.w);
            af[4] = f2bf(u1.x); af[5] = f2bf(u1.y);
            af[6] = f2bf(u1.z); af[7] = f2bf(u1.w);
            #pragma unroll
            for (int nt = 0; nt < 4; ++nt)
                acc[nt] = __builtin_amdgcn_mfma_f32_16x16x32_bf16(
                    af, bfr[kk][nt], acc[nt], 0, 0, 0);
        }

        const float av0 = a_src[col], av1 = a_src[16 + col];
        const float av2 = a_src[32 + col], av3 = a_src[48 + col];
        const float bv0 = a_dst[col], bv1 = a_dst[16 + col];
        const float bv2 = a_dst[32 + col], bv3 = a_dst[48 + col];

        float ps[4], pd[4];
        #pragma unroll
        for (int reg = 0; reg < 4; ++reg) {
            ps[reg] = acc[0][reg] * av0 + acc[1][reg] * av1
                    + acc[2][reg] * av2 + acc[3][reg] * av3;
            pd[reg] = acc[0][reg] * bv0 + acc[1][reg] * bv1
                    + acc[2][reg] * bv2 + acc[3][reg] * bv3;
        }

        #pragma unroll
        for (int nt = 0; nt < 4; ++nt)
            #pragma unroll
            for (int reg = 0; reg < 4; ++reg)
                Whb[(size_t)(row0 + quad * 4 + reg) * FOUT + nt * 16 + col] =
                    __float2bfloat16(acc[nt][reg]);

        #pragma unroll
        for (int off = 1; off < 16; off <<= 1) {
            #pragma unroll
            for (int reg = 0; reg < 4; ++reg) {
                ps[reg] += __shfl_xor(ps[reg], off);
                pd[reg] += __shfl_xor(pd[reg], off);
            }
        }
        if (col == 0) {
            #pragma unroll
            for (int reg = 0; reg < 4; ++reg) {
                s_src[row0 + quad * 4 + reg] = ps[reg];
                s_dst[row0 + quad * 4 + reg] = pd[reg];
            }
        }
        return;
    }

    // ---------------- TILESORT role ----------------
    const int tile = blockIdx.x;
    const int base = tile * TS;
    const int tcnt = (NE - base < TS) ? (NE - base) : TS;

    cnt[tid] = 0; cnt[tid + 512] = 0;
    __syncthreads();

    unsigned pk[8];
    #pragma unroll
    for (int j = 0; j < 8; ++j) {
        const int i = j * 512 + tid;
        if (i < tcnt) {
            const int e = base + i;
            const unsigned s = (unsigned)__builtin_nontemporal_load(ei + e);
            const unsigned d = (unsigned)__builtin_nontemporal_load(ei + NE + e);
            pk[j] = (s << 16) | d;
            atomicAdd(&cnt[d / DPB], 1);
        } else pk[j] = 0xFFFFFFFFu;
    }
    __syncthreads();

    // exclusive scan of cnt[0..1024): 2 bins/thread, wave scans + combine;
    // then allocate each non-empty segment's global slab position.
    {
        const int i0 = tid * 2;
        const int v0 = cnt[i0], v1 = cnt[i0 + 1];
        const int s = v0 + v1;
        int inc = s;
        #pragma unroll
        for (int off = 1; off < 64; off <<= 1) {
            const int t = __shfl_up(inc, off);
            if (lane >= off) inc += t;
        }
        if (lane == 63) wsum[wv] = inc;
        __syncthreads();
        int wb = 0;
        #pragma unroll
        for (int w = 0; w < 7; ++w) if (w < wv) wb += wsum[w];
        const int excl = wb + inc - s;
        ofs[i0]     = excl;      ofs[i0 + 1] = excl + v0;
        cur[i0]     = excl;      cur[i0 + 1] = excl + v0;
        if (v0 > 0) gpos[i0]     = i0 * PADCAP + atomicAdd(&bcur[i0], v0);
        if (v1 > 0) gpos[i0 + 1] = (i0 + 1) * PADCAP + atomicAdd(&bcur[i0 + 1], v1);
    }
    __syncthreads();

    // LDS scatter into bucket order
    #pragma unroll
    for (int j = 0; j < 8; ++j) {
        if (pk[j] != 0xFFFFFFFFu) {
            const int b = (int)(pk[j] & 0xffffu) / DPB;
            const int pos = atomicAdd(&cur[b], 1);
            srt[pos] = pk[j];
        }
    }
    __syncthreads();

    // segment write-out: consecutive i within a segment -> consecutive
    // global addresses (near-coalesced). Guarded against slab overflow.
    for (int i = tid; i < tcnt; i += 512) {
        const unsigned p = srt[i];
        const int bb = (int)(p & 0xffffu) / DPB;
        const int dpos = gpos[bb] + (i - ofs[bb]);
        if (dpos < (bb + 1) * PADCAP) bdata2[dpos] = p;
    }
}

// Per-bucket gather (50 dsts, ~1000 edges), 512 threads, grid 1000
// (~3.9 blocks/CU — fixes r9's 31% occupancy). Slab read is exclusive to
// this block and fully coalesced (~2 iterations); LDS counting-sort by dst
// with fused ev = exp(lrelu(s_src+s_dst)); wave=dst/lane=feature gather
// (unroll 8), normalize + ELU fused. No global atomics.
__global__ __launch_bounds__(512) void k_sortgather(
    const int* __restrict__ bcur, const unsigned* __restrict__ bdata2,
    const float* __restrict__ s_src, const float* __restrict__ s_dst,
    const __hip_bfloat16* __restrict__ Whb, float* __restrict__ out)
{
    __shared__ unsigned raw[PADCAP];   // 5.1 KB
    __shared__ unsigned srt[PADCAP];   // 5.1 KB
    __shared__ float evs[PADCAP];      // 5.1 KB
    __shared__ float sdl[DPB];
    __shared__ int cnt[64];
    __shared__ int ofs2[65];
    __shared__ int cur[64];

    const int b = blockIdx.x;
    const int tid = threadIdx.x;
    const int lane = tid & 63;
    const int wv = tid >> 6;
    const int d0 = b * DPB;

    if (tid < 64) cnt[tid] = 0;
    if (tid < DPB) sdl[tid] = s_dst[d0 + tid];

    int tot = bcur[b];
    if (tot > PADCAP) tot = PADCAP;    // defensive (8.9-sigma headroom)
    const unsigned* slab = bdata2 + (size_t)b * PADCAP;

    for (int i = tid; i < tot; i += 512) raw[i] = slab[i];
    __syncthreads();

    for (int i = tid; i < tot; i += 512)
        atomicAdd(&cnt[(int)(raw[i] & 0xffffu) - d0], 1);
    __syncthreads();

    // exclusive scan over 64 bins (wave 0)
    if (tid < 64) {
        const int cc = (tid < DPB) ? cnt[tid] : 0;
        int in2 = cc;
        #pragma unroll
        for (int off = 1; off < 64; off <<= 1) {
            const int t = __shfl_up(in2, off);
            if (tid >= off) in2 += t;
        }
        ofs2[tid + 1] = in2;
        if (tid == 0) ofs2[0] = 0;
        cur[tid] = in2 - cc;
    }
    __syncthreads();

    // LDS scatter into dst order + fused ev compute
    for (int i = tid; i < tot; i += 512) {
        const unsigned p = raw[i];
        const int j = (int)(p & 0xffffu) - d0;
        const int pos = atomicAdd(&cur[j], 1);
        srt[pos] = p;
        float v = s_src[p >> 16] + sdl[j];
        v = (v > 0.f) ? v : NEG * v;
        evs[pos] = __expf(v);
    }
    __syncthreads();

    // gather: wave = dst, lane = feature; unroll 8 (8 Whb rows in flight)
    for (int j = wv; j < DPB; j += 8) {
        const int d = d0 + j;
        const int beg = ofs2[j];
        const int end = ofs2[j + 1];
        float acc = 0.f, den = 0.f;
        int i = beg;
        for (; i + 8 <= end; i += 8) {
            int ss[8]; float ee[8], w[8];
            #pragma unroll
            for (int k = 0; k < 8; ++k) {
                ss[k] = (int)(srt[i + k] >> 16);
                ee[k] = evs[i + k];
            }
            #pragma unroll
            for (int k = 0; k < 8; ++k)
                w[k] = __bfloat162float(Whb[(size_t)ss[k] * FOUT + lane]);
            #pragma unroll
            for (int k = 0; k < 8; ++k) {
                acc = fmaf(ee[k], w[k], acc);
                den += ee[k];
            }
        }
        for (; i < end; ++i) {
            const int s0 = (int)(srt[i] >> 16);
            const float e0 = evs[i];
            acc = fmaf(e0, __bfloat162float(Whb[(size_t)s0 * FOUT + lane]), acc);
            den += e0;
        }
        const float r = acc / (den + 1e-16f);
        out[(size_t)d * FOUT + lane] = (r > 0.f) ? r : expm1f(r);
    }
}

extern "C" void kernel_launch(void* const* d_in, const int* in_sizes, int n_in,
                              void* d_out, int out_size, void* d_ws, size_t ws_size,
                              hipStream_t stream)
{
    const float* x     = (const float*)d_in[0];
    const int*   ei    = (const int*)d_in[1];   // [2,E]: src = ei[0..E), dst = ei[E..2E)
    const float* W     = (const float*)d_in[2];
    const float* a_src = (const float*)d_in[3];
    const float* a_dst = (const float*)d_in[4];
    float* out = (float*)d_out;

    // Workspace: Whb 6.4 MB | s_src 200 KB | s_dst 200 KB | bcur 4 KB |
    // bdata2 5.24 MB  -> ~12 MB. Only bcur needs zeroing.
    float* ws    = (float*)d_ws;
    __hip_bfloat16* Whb = (__hip_bfloat16*)ws;
    float* s_src = ws + (size_t)NN * FOUT / 2;
    float* s_dst = s_src + NN;
    int*   bcur  = (int*)(s_dst + NN);
    unsigned* bdata2 = (unsigned*)(bcur + NB);

    hipMemsetAsync(bcur, 0, NB * sizeof(int), stream);
    k_front<<<TILE_BLKS + GEMM_BLKS, 512, 0, stream>>>(
        x, W, a_src, a_dst, ei, Whb, s_src, s_dst, bcur, bdata2);
    k_sortgather<<<NBUSED, 512, 0, stream>>>(bcur, bdata2, s_src, s_dst,
                                             Whb, out);
}